// Round 9
// baseline (158.089 us; speedup 1.0000x reference)
//
#include <hip/hip_runtime.h>

// Head attention, B=4 T=4096 C=1024 H=64. f32 in/out, bf16 MFMA compute.
// scores = k @ q^T (reference quirk).
// Counter-backed design rules:
//  - r4..r18: see journal. r17: KVBLK=128+swapped QK (151->149). r18: single
//    dispatch round, chunk 1024 (149->147).
//  - r19 (this round): pair-fused attention. Tile 63-p's s-range is a superset of
//    tile p's -> one block stages Q/V once and computes BOTH K-tiles against it.
//    Block-steps 4224->3136 (-26% staging/barriers/global reads), blocks 640->448.
//    MFMA work unchanged; Ps reused sequentially (wave-private ordering).

typedef __attribute__((ext_vector_type(8))) short short8;
typedef __attribute__((ext_vector_type(4))) short s16x4;
typedef __attribute__((ext_vector_type(4))) float f32x4;
typedef unsigned short u16;

#define MFMA16(A, B, C) __builtin_amdgcn_mfma_f32_16x16x32_bf16((A), (B), (C), 0, 0, 0)

__device__ __forceinline__ u16 f2b(float f) {
    __bf16 h = (__bf16)f;                     // RNE hw convert; backend pk-fuses pairs
    return __builtin_bit_cast(u16, h);
}
__device__ __forceinline__ float b2f(u16 v) {
    return __builtin_bit_cast(float, (unsigned int)v << 16);
}

__device__ __forceinline__ void gload16(const void* g, void* l) {
    __builtin_amdgcn_global_load_lds(
        (const __attribute__((address_space(1))) unsigned int*)g,
        (__attribute__((address_space(3))) unsigned int*)l, 16, 0, 0);
}

// ---------- kernel 1: W -> fragment-ordered WtF, 8 replicas.
// WtF[rep][t][kc][lane][j], t = mat*4 + tl in 0..11, kc in 0..31, lane = quad*16+l16.
// element = bf16( W_mat[ k = kc*32 + quad*8 + j ][ h = tl*16 + l16 ] )
__global__ __launch_bounds__(256) void wt_kernel(const float* __restrict__ Wk,
                                                 const float* __restrict__ Wq,
                                                 const float* __restrict__ Wv,
                                                 u16* __restrict__ WtF) {
    const int kc = blockIdx.x;       // 0..31
    const int mat = blockIdx.y;      // 0..2
    const float* W = (mat == 0) ? Wk : (mat == 1 ? Wq : Wv);
    const int tid = threadIdx.x;
    const int tl = tid >> 6, lane = tid & 63, quad = lane >> 4, l16 = lane & 15;
    short8 v;
#pragma unroll
    for (int j = 0; j < 8; ++j)
        v[j] = f2b(W[(size_t)(kc * 32 + quad * 8 + j) * 64 + tl * 16 + l16]);
    const size_t dst = ((size_t)((mat * 4 + tl) * 32 + kc) * 64 + lane) * 8;
#pragma unroll
    for (int rep = 0; rep < 8; ++rep)
        *(short8*)(WtF + (size_t)rep * 196608 + dst) = v;
}

// ---------- kernel 2: fused projection. 512 blocks x 32 rows, N=192 whole.
// LDS: As[2][32][256B] f32 (col-swizzled via source addr), Bs[2][12][2][64][16B] bf16.
// Per wave: 2 row-tiles x 3 col-tiles; BK=64 (2 MFMA k-subchunks). 2-phase pipeline.
__global__ __launch_bounds__(256) void proj_kernel(const float* __restrict__ x,
                                                   const u16* __restrict__ WtF,
                                                   u16* __restrict__ Kb,
                                                   u16* __restrict__ Qb,
                                                   u16* __restrict__ Vt) {
    __shared__ char smem[65536];                     // As: 0..16K (2x8K), Bs: 16K..64K (2x24K)
    const int tid = threadIdx.x;
    const int w = tid >> 6, lane = tid & 63, quad = lane >> 4, l16 = lane & 15;
    const int mbase = blockIdx.x * 32;
    const u16* Wrep = WtF + (size_t)(blockIdx.x & 7) * 196608;  // XCD-local replica
    const char* xblk = (const char*)x + (size_t)mbase * 4096;
    const int wbase16 = (w << 6) * 16;               // wave-uniform LDS unit base (bytes)

    f32x4 acc[2][3];
#pragma unroll
    for (int r = 0; r < 2; ++r)
#pragma unroll
        for (int c = 0; c < 3; ++c) acc[r][c] = (f32x4)(0.0f);

    // stage chunk p into buffer buf: A = 512 units (16B), B = 1536 units (16B)
#define STAGE(buf, p) do {                                                          \
        char* la = smem + (buf) * 8192;                                             \
        char* lb = smem + 16384 + (buf) * 24576;                                    \
        _Pragma("unroll")                                                           \
        for (int i = 0; i < 2; ++i) {                                               \
            int u = i * 256 + tid;                                                  \
            int row = u >> 4;                                                       \
            int cb = ((u & 15) * 16) ^ ((row & 7) << 5);                            \
            gload16(xblk + (size_t)row * 4096 + (size_t)(p) * 256 + cb,             \
                    la + i * 4096 + wbase16);                                       \
        }                                                                           \
        _Pragma("unroll")                                                           \
        for (int i = 0; i < 6; ++i) {                                               \
            int u = i * 256 + tid;                                                  \
            gload16(Wrep + (size_t)(u >> 7) * 16384 + (size_t)(p) * 1024 + (u & 127) * 8, \
                    lb + i * 4096 + wbase16);                                       \
        }                                                                           \
    } while (0)

    STAGE(0, 0);
    __syncthreads();

    for (int t = 0; t < 16; ++t) {
        const int cur = t & 1;
        if (t < 15) STAGE(cur ^ 1, t + 1);           // async prefetch next chunk
        const char* Ab = smem + cur * 8192;
        const char* Bb = smem + 16384 + cur * 24576;
#pragma unroll
        for (int kk = 0; kk < 2; ++kk) {
            short8 af[2];
#pragma unroll
            for (int r = 0; r < 2; ++r) {
                const int row = r * 16 + l16;
                const int c0 = (kk * 128 + quad * 32) ^ ((l16 & 7) << 5);
                f32x4 lo = *(const f32x4*)(Ab + row * 256 + c0);
                f32x4 hi = *(const f32x4*)(Ab + row * 256 + (c0 ^ 16));
                short8 a;
#pragma unroll
                for (int j = 0; j < 4; ++j) {
                    a[j]     = (short)f2b(lo[j]);
                    a[j + 4] = (short)f2b(hi[j]);
                }
                af[r] = a;
            }
#pragma unroll
            for (int c = 0; c < 3; ++c) {
                short8 bf = *(const short8*)(Bb + (((w * 3 + c) * 2 + kk) * 64 + lane) * 16);
                acc[0][c] = MFMA16(af[0], bf, acc[0][c]);
                acc[1][c] = MFMA16(af[1], bf, acc[1][c]);
            }
        }
        __syncthreads();                             // drains vmcnt (stage) + lgkm, swap
    }
#undef STAGE

    // epilogue: bounce through LDS tile[32][200], then Kb, 4x Qb, 4x Vt (transposed)
    u16 (*tile)[200] = (u16(*)[200])smem;
#pragma unroll
    for (int r = 0; r < 2; ++r)
#pragma unroll
        for (int c = 0; c < 3; ++c)
#pragma unroll
            for (int reg = 0; reg < 4; ++reg)
                tile[r * 16 + quad * 4 + reg][(w * 3 + c) * 16 + l16] = f2b(acc[r][c][reg]);
    __syncthreads();

    const int b = mbase >> 12, t0b = mbase & 4095;
    {
        const int row = tid >> 3, cu8 = (tid & 7) * 8;
        short8 vk = *(const short8*)&tile[row][cu8];
        *(short8*)(Kb + (size_t)(mbase + row) * 64 + cu8) = vk;
        short8 vq = *(const short8*)&tile[row][64 + cu8];
#pragma unroll
        for (int r = 0; r < 4; ++r)
            *(short8*)(Qb + (size_t)r * 1048576 + (size_t)(mbase + row) * 64 + cu8) = vq;
    }
    {
        const int h = tid >> 2, toff = (tid & 3) * 8;
        short8 vv;
#pragma unroll
        for (int j = 0; j < 8; ++j) vv[j] = tile[toff + j][128 + h];
#pragma unroll
        for (int r = 0; r < 4; ++r)
            *(short8*)(Vt + (size_t)r * 1048576 + ((size_t)(b * 64 + h) << 12) + t0b + toff) = vv;
    }
}

// ---------- kernel 3: pair-fused split-S flash attention, KVBLK=128, swapped QK.
// One block handles tiles (p, 63-p): stage Q/V once per s-block, compute both K-tiles.
#define QSWZ(row, cb) ((row) * 128 + ((cb) ^ (((row) & 7) << 4)))
#define VSWZ(row, cb) ((row) * 256 + ((cb) ^ (((row) & 15) << 4)))
__global__ __launch_bounds__(256) void attn_kernel(const u16* __restrict__ Kb,
                                                   const u16* __restrict__ Qb,
                                                   const u16* __restrict__ Vt,
                                                   u16* __restrict__ Op,
                                                   float* __restrict__ Ml) {
    const int pc = blockIdx.x;                       // 0..111
    const int b = blockIdx.y;
    int p, c;
    if (pc < 64) { p = pc >> 2; c = pc & 3; }        // p 0..15: 4 chunks each
    else { int i = pc - 64; p = 16 + i / 3; c = i - (p - 16) * 3; }  // p 16..31: 3
    const int tLo = p, tHi = 63 - p;
    const int nLow = (p >> 4) + 1;                   // lo-active chunk count
    const bool hasLo = (c < nLow);
    __shared__ char smem[50176];                     // Qs 16K | Vs 16K | Ps 4x4352
    const int tid = threadIdx.x;
    const int w = tid >> 6, lane = tid & 63, quad = lane >> 4, l16 = lane & 15;
    char* psB = smem + 32768 + w * 4352;             // wave-private P
    const int bsBeg = c * 8;
    const int bsDiagLo = tLo >> 1, bsDiagHi = tHi >> 1;
    const int bsEnd = min(c * 8 + 7, bsDiagHi);

    // replica: simultaneous readers of an s-block differ in p -> spread x4
    const u16* Qp = Qb + (size_t)(p & 3) * 1048576;
    const u16* Vp = Vt + (size_t)(p & 3) * 1048576;

    // staging addresses: 1024 16B-units; Q: row=lin>>3 (128), V: row h=lin>>4 (64)
    int qd[4], vd[4];
    size_t qg[4], vg[4];
#pragma unroll
    for (int i = 0; i < 4; ++i) {
        const int lin = tid + i * 256;
        qd[i] = QSWZ(lin >> 3, (lin & 7) * 16);
        vd[i] = VSWZ(lin >> 4, (lin & 15) * 16);
        qg[i] = ((size_t)(b << 12) + (lin >> 3)) * 64 + (lin & 7) * 8;
        vg[i] = ((size_t)(b * 64 + (lin >> 4)) << 12) + (lin & 15) * 8;
    }

    short8 aKlo[2], aKhi[2];
#pragma unroll
    for (int kk = 0; kk < 2; ++kk) {
        aKlo[kk] = *(const short8*)(Kb + (size_t)((b << 12) + tLo * 64 + w * 16 + l16) * 64 + kk * 32 + quad * 8);
        aKhi[kk] = *(const short8*)(Kb + (size_t)((b << 12) + tHi * 64 + w * 16 + l16) * 64 + kk * 32 + quad * 8);
    }

    short8 qr[4], vr[4];
#pragma unroll
    for (int i = 0; i < 4; ++i) {
        qr[i] = *(const short8*)(Qp + qg[i] + (size_t)bsBeg * 8192);
        vr[i] = *(const short8*)(Vp + vg[i] + bsBeg * 128);
    }

    float lLo = 0.0f, lHi = 0.0f;                    // lane's t-row = w*16+l16
    f32x4 Olo[4], Ohi[4];
#pragma unroll
    for (int ht = 0; ht < 4; ++ht) { Olo[ht] = (f32x4)(0.0f); Ohi[ht] = (f32x4)(0.0f); }

    const int tgLo = tLo * 64 + w * 16 + l16;
    const int tgHi = tHi * 64 + w * 16 + l16;

    for (int bs = bsBeg; bs <= bsEnd; ++bs) {
        __syncthreads();                              // prev step's LDS reads done
#pragma unroll
        for (int i = 0; i < 4; ++i) {
            *(short8*)(smem + qd[i]) = qr[i];
            *(short8*)(smem + 16384 + vd[i]) = vr[i];
        }
        __syncthreads();
        if (bs < bsEnd) {                             // next-step loads fly during compute
#pragma unroll
            for (int i = 0; i < 4; ++i) {
                qr[i] = *(const short8*)(Qp + qg[i] + (size_t)(bs + 1) * 8192);
                vr[i] = *(const short8*)(Vp + vg[i] + (bs + 1) * 128);
            }
        }
        const bool doLo = hasLo && (bs <= bsDiagLo);  // block-uniform

        // ---- process one K-tile against the staged s-block (macro-free lambda)
#define TILE_PASS(aK, diagBs, tg, l_acc, O)                                          \
        do {                                                                         \
            f32x4 sc[8];                                                             \
            _Pragma("unroll")                                                        \
            for (int nt = 0; nt < 8; ++nt) sc[nt] = (f32x4)(0.0f);                   \
            _Pragma("unroll")                                                        \
            for (int kk = 0; kk < 2; ++kk)                                           \
                _Pragma("unroll")                                                    \
                for (int nt = 0; nt < 8; ++nt) {                                     \
                    short8 aq = *(const short8*)(smem + QSWZ(nt * 16 + l16, kk * 64 + quad * 16)); \
                    sc[nt] = MFMA16(aq, (aK), sc[nt]);                               \
                }                                                                    \
            _Pragma("unroll")                                                        \
            for (int nt = 0; nt < 8; ++nt) {                                         \
                const int sgBase = bs * 128 + nt * 16 + quad * 4;                    \
                s16x4 v4;                                                            \
                _Pragma("unroll")                                                    \
                for (int reg = 0; reg < 4; ++reg) {                                  \
                    float v = sc[nt][reg];                                           \
                    if (bs == (diagBs) && sgBase + reg > (tg)) v = -1e30f;           \
                    float pp = exp2f(v * 0.18033688011112042f);                      \
                    (l_acc) += pp;                                                   \
                    v4[reg] = (short)f2b(pp);                                        \
                }                                                                    \
                *(s16x4*)(psB + l16 * 272 + nt * 32 + quad * 8) = v4;                \
            }                                                                        \
            _Pragma("unroll")                                                        \
            for (int kk = 0; kk < 4; ++kk) {                                         \
                short8 ap = *(const short8*)(psB + l16 * 272 + kk * 64 + quad * 16); \
                _Pragma("unroll")                                                    \
                for (int ht = 0; ht < 4; ++ht) {                                     \
                    short8 bv = *(const short8*)(smem + 16384 + VSWZ(ht * 16 + l16, kk * 64 + quad * 16)); \
                    (O)[ht] = MFMA16(ap, bv, (O)[ht]);                               \
                }                                                                    \
            }                                                                        \
        } while (0)

        {   // hi tile always; per-kk A-operand selected inside
            f32x4 sc[8];
#pragma unroll
            for (int nt = 0; nt < 8; ++nt) sc[nt] = (f32x4)(0.0f);
#pragma unroll
            for (int kk = 0; kk < 2; ++kk)
#pragma unroll
                for (int nt = 0; nt < 8; ++nt) {
                    short8 aq = *(const short8*)(smem + QSWZ(nt * 16 + l16, kk * 64 + quad * 16));
                    sc[nt] = MFMA16(aq, aKhi[kk], sc[nt]);
                }
#pragma unroll
            for (int nt = 0; nt < 8; ++nt) {
                const int sgBase = bs * 128 + nt * 16 + quad * 4;
                s16x4 v4;
#pragma unroll
                for (int reg = 0; reg < 4; ++reg) {
                    float v = sc[nt][reg];
                    if (bs == bsDiagHi && sgBase + reg > tgHi) v = -1e30f;
                    float pp = exp2f(v * 0.18033688011112042f);
                    lHi += pp;
                    v4[reg] = (short)f2b(pp);
                }
                *(s16x4*)(psB + l16 * 272 + nt * 32 + quad * 8) = v4;
            }
#pragma unroll
            for (int kk = 0; kk < 4; ++kk) {
                short8 ap = *(const short8*)(psB + l16 * 272 + kk * 64 + quad * 16);
#pragma unroll
                for (int ht = 0; ht < 4; ++ht) {
                    short8 bv = *(const short8*)(smem + 16384 + VSWZ(ht * 16 + l16, kk * 64 + quad * 16));
                    Ohi[ht] = MFMA16(ap, bv, Ohi[ht]);
                }
            }
        }
        if (doLo) {
            f32x4 sc[8];
#pragma unroll
            for (int nt = 0; nt < 8; ++nt) sc[nt] = (f32x4)(0.0f);
#pragma unroll
            for (int kk = 0; kk < 2; ++kk)
#pragma unroll
                for (int nt = 0; nt < 8; ++nt) {
                    short8 aq = *(const short8*)(smem + QSWZ(nt * 16 + l16, kk * 64 + quad * 16));
                    sc[nt] = MFMA16(aq, aKlo[kk], sc[nt]);
                }
#pragma unroll
            for (int nt = 0; nt < 8; ++nt) {
                const int sgBase = bs * 128 + nt * 16 + quad * 4;
                s16x4 v4;
#pragma unroll
                for (int reg = 0; reg < 4; ++reg) {
                    float v = sc[nt][reg];
                    if (bs == bsDiagLo && sgBase + reg > tgLo) v = -1e30f;
                    float pp = exp2f(v * 0.18033688011112042f);
                    lLo += pp;
                    v4[reg] = (short)f2b(pp);
                }
                *(s16x4*)(psB + l16 * 272 + nt * 32 + quad * 8) = v4;
            }
#pragma unroll
            for (int kk = 0; kk < 4; ++kk) {
                short8 ap = *(const short8*)(psB + l16 * 272 + kk * 64 + quad * 16);
#pragma unroll
                for (int ht = 0; ht < 4; ++ht) {
                    short8 bv = *(const short8*)(smem + 16384 + VSWZ(ht * 16 + l16, kk * 64 + quad * 16));
                    Olo[ht] = MFMA16(ap, bv, Olo[ht]);
                }
            }
        }
#undef TILE_PASS
    }

    const int trow = w * 16 + quad * 4;
    {   // hi epilogue (always)
        const int slot = ((b * 64 + tHi) * 4 + c);
        float v = lHi;
        v += __shfl_xor(v, 16);
        v += __shfl_xor(v, 32);
        if (quad == 0) Ml[(size_t)slot * 64 + w * 16 + l16] = v;
#pragma unroll
        for (int ht = 0; ht < 4; ++ht)
#pragma unroll
            for (int reg = 0; reg < 4; ++reg)
                Op[(size_t)slot * 4096 + (size_t)(trow + reg) * 64 + ht * 16 + l16] = f2b(Ohi[ht][reg]);
    }
    if (hasLo) {                                     // lo epilogue
        const int slot = ((b * 64 + tLo) * 4 + c);
        float v = lLo;
        v += __shfl_xor(v, 16);
        v += __shfl_xor(v, 32);
        if (quad == 0) Ml[(size_t)slot * 64 + w * 16 + l16] = v;
#pragma unroll
        for (int ht = 0; ht < 4; ++ht)
#pragma unroll
            for (int reg = 0; reg < 4; ++reg)
                Op[(size_t)slot * 4096 + (size_t)(trow + reg) * 64 + ht * 16 + l16] = f2b(Olo[ht][reg]);
    }
}

// ---------- kernel 4: combine — plain sums over 4 chunk slots, divide
__global__ __launch_bounds__(256) void combine_kernel(const u16* __restrict__ Op,
                                                      const float* __restrict__ Ml,
                                                      float* __restrict__ out) {
    const int tid = threadIdx.x, cu = tid & 7, r0 = tid >> 3;
    const int tile = blockIdx.x, b = blockIdx.y;
    const int nch = tile / 16 + 1;
    const int slotBase = (b * 64 + tile) * 4;
#pragma unroll
    for (int i = 0; i < 2; ++i) {
        const int row = r0 + 32 * i;
        float L = 0.0f, acc[8];
#pragma unroll
        for (int j = 0; j < 8; ++j) acc[j] = 0.0f;
#pragma unroll
        for (int c = 0; c < 4; ++c) {
            const bool act = c < nch;
            float lraw = Ml[(size_t)(slotBase + c) * 64 + row];
            short8 ov = *(const short8*)(Op + (size_t)(slotBase + c) * 4096 + (size_t)row * 64 + cu * 8);
            L += act ? lraw : 0.0f;
#pragma unroll
            for (int j = 0; j < 8; ++j)
                acc[j] += act ? b2f((u16)ov[j]) : 0.0f;
        }
        float inv = 1.0f / L;
        float* dst = out + ((size_t)(b << 12) + tile * 64 + row) * 64 + cu * 8;
        *(float4*)(dst)     = make_float4(acc[0] * inv, acc[1] * inv, acc[2] * inv, acc[3] * inv);
        *(float4*)(dst + 4) = make_float4(acc[4] * inv, acc[5] * inv, acc[6] * inv, acc[7] * inv);
    }
}

extern "C" void kernel_launch(void* const* d_in, const int* in_sizes, int n_in,
                              void* d_out, int out_size, void* d_ws, size_t ws_size,
                              hipStream_t stream) {
    const float* x  = (const float*)d_in[0];
    const float* Wk = (const float*)d_in[1];
    const float* Wq = (const float*)d_in[2];
    const float* Wv = (const float*)d_in[3];

    u16* ws16 = (u16*)d_ws;
    u16* Wt = ws16;                          // 8 * 196608  = 1,572,864 u16 (3.1 MB)
    u16* Kb = Wt + 1572864;                  // 1,048,576          (2 MB)
    u16* Qb = Kb + 1048576;                  // 4 * 1,048,576      (8 MB, replicas)
    u16* Vt = Qb + 4194304;                  // 4 * 1,048,576      (8 MB, replicas)
    u16* Op = Vt + 4194304;                  // 4,194,304          (8.4 MB, 1024 slots)
    float* Ml = (float*)(Op + 8388608);      // 65,536 f32         (0.25 MB)
    // total ws ~38.6 MB (Op region oversized, harmless)

    wt_kernel<<<dim3(32, 3), 256, 0, stream>>>(Wk, Wq, Wv, Wt);
    proj_kernel<<<512, 256, 0, stream>>>(x, Wt, Kb, Qb, Vt);
    attn_kernel<<<dim3(112, 4), 256, 0, stream>>>(Kb, Qb, Vt, Op, Ml);
    combine_kernel<<<dim3(64, 4), 256, 0, stream>>>(Op, Ml, (float*)d_out);
}

// Round 10
// 151.279 us; speedup vs baseline: 1.0450x; 1.0450x over previous
//
#include <hip/hip_runtime.h>

// Head attention, B=4 T=4096 C=1024 H=64. f32 in/out, bf16 MFMA compute.
// scores = k @ q^T (reference quirk).
// Counter-backed design rules:
//  - r4..r18: see journal. r18: single dispatch round, chunk 1024 (149->147).
//  - r19: pair-fusion REGRESSED (158, occupancy 9.3%, imbalance) -> reverted.
//  - r20 (this round): r9 counters: VALUBusy 28-30% vs MfmaUtil 7% -> softmax VALU
//    chain is the widest per-step cost. (1) causal mask hoisted to block-uniform
//    diag-step branch (-64 VALU/step on 7 of 8 steps); (2) l-sum via ones-MFMA
//    (P @ 1) in the PV loop: kills 32 serial adds/step + epilogue shuffles.

typedef __attribute__((ext_vector_type(8))) short short8;
typedef __attribute__((ext_vector_type(4))) short s16x4;
typedef __attribute__((ext_vector_type(4))) float f32x4;
typedef unsigned short u16;

#define MFMA16(A, B, C) __builtin_amdgcn_mfma_f32_16x16x32_bf16((A), (B), (C), 0, 0, 0)

__device__ __forceinline__ u16 f2b(float f) {
    __bf16 h = (__bf16)f;                     // RNE hw convert; backend pk-fuses pairs
    return __builtin_bit_cast(u16, h);
}
__device__ __forceinline__ float b2f(u16 v) {
    return __builtin_bit_cast(float, (unsigned int)v << 16);
}

__device__ __forceinline__ void gload16(const void* g, void* l) {
    __builtin_amdgcn_global_load_lds(
        (const __attribute__((address_space(1))) unsigned int*)g,
        (__attribute__((address_space(3))) unsigned int*)l, 16, 0, 0);
}

// ---------- kernel 1: W -> fragment-ordered WtF, 8 replicas.
// WtF[rep][t][kc][lane][j], t = mat*4 + tl in 0..11, kc in 0..31, lane = quad*16+l16.
// element = bf16( W_mat[ k = kc*32 + quad*8 + j ][ h = tl*16 + l16 ] )
__global__ __launch_bounds__(256) void wt_kernel(const float* __restrict__ Wk,
                                                 const float* __restrict__ Wq,
                                                 const float* __restrict__ Wv,
                                                 u16* __restrict__ WtF) {
    const int kc = blockIdx.x;       // 0..31
    const int mat = blockIdx.y;      // 0..2
    const float* W = (mat == 0) ? Wk : (mat == 1 ? Wq : Wv);
    const int tid = threadIdx.x;
    const int tl = tid >> 6, lane = tid & 63, quad = lane >> 4, l16 = lane & 15;
    short8 v;
#pragma unroll
    for (int j = 0; j < 8; ++j)
        v[j] = f2b(W[(size_t)(kc * 32 + quad * 8 + j) * 64 + tl * 16 + l16]);
    const size_t dst = ((size_t)((mat * 4 + tl) * 32 + kc) * 64 + lane) * 8;
#pragma unroll
    for (int rep = 0; rep < 8; ++rep)
        *(short8*)(WtF + (size_t)rep * 196608 + dst) = v;
}

// ---------- kernel 2: fused projection. 512 blocks x 32 rows, N=192 whole.
// LDS: As[2][32][256B] f32 (col-swizzled via source addr), Bs[2][12][2][64][16B] bf16.
// Per wave: 2 row-tiles x 3 col-tiles; BK=64 (2 MFMA k-subchunks). 2-phase pipeline.
__global__ __launch_bounds__(256) void proj_kernel(const float* __restrict__ x,
                                                   const u16* __restrict__ WtF,
                                                   u16* __restrict__ Kb,
                                                   u16* __restrict__ Qb,
                                                   u16* __restrict__ Vt) {
    __shared__ char smem[65536];                     // As: 0..16K (2x8K), Bs: 16K..64K (2x24K)
    const int tid = threadIdx.x;
    const int w = tid >> 6, lane = tid & 63, quad = lane >> 4, l16 = lane & 15;
    const int mbase = blockIdx.x * 32;
    const u16* Wrep = WtF + (size_t)(blockIdx.x & 7) * 196608;  // XCD-local replica
    const char* xblk = (const char*)x + (size_t)mbase * 4096;
    const int wbase16 = (w << 6) * 16;               // wave-uniform LDS unit base (bytes)

    f32x4 acc[2][3];
#pragma unroll
    for (int r = 0; r < 2; ++r)
#pragma unroll
        for (int c = 0; c < 3; ++c) acc[r][c] = (f32x4)(0.0f);

    // stage chunk p into buffer buf: A = 512 units (16B), B = 1536 units (16B)
#define STAGE(buf, p) do {                                                          \
        char* la = smem + (buf) * 8192;                                             \
        char* lb = smem + 16384 + (buf) * 24576;                                    \
        _Pragma("unroll")                                                           \
        for (int i = 0; i < 2; ++i) {                                               \
            int u = i * 256 + tid;                                                  \
            int row = u >> 4;                                                       \
            int cb = ((u & 15) * 16) ^ ((row & 7) << 5);                            \
            gload16(xblk + (size_t)row * 4096 + (size_t)(p) * 256 + cb,             \
                    la + i * 4096 + wbase16);                                       \
        }                                                                           \
        _Pragma("unroll")                                                           \
        for (int i = 0; i < 6; ++i) {                                               \
            int u = i * 256 + tid;                                                  \
            gload16(Wrep + (size_t)(u >> 7) * 16384 + (size_t)(p) * 1024 + (u & 127) * 8, \
                    lb + i * 4096 + wbase16);                                       \
        }                                                                           \
    } while (0)

    STAGE(0, 0);
    __syncthreads();

    for (int t = 0; t < 16; ++t) {
        const int cur = t & 1;
        if (t < 15) STAGE(cur ^ 1, t + 1);           // async prefetch next chunk
        const char* Ab = smem + cur * 8192;
        const char* Bb = smem + 16384 + cur * 24576;
#pragma unroll
        for (int kk = 0; kk < 2; ++kk) {
            short8 af[2];
#pragma unroll
            for (int r = 0; r < 2; ++r) {
                const int row = r * 16 + l16;
                const int c0 = (kk * 128 + quad * 32) ^ ((l16 & 7) << 5);
                f32x4 lo = *(const f32x4*)(Ab + row * 256 + c0);
                f32x4 hi = *(const f32x4*)(Ab + row * 256 + (c0 ^ 16));
                short8 a;
#pragma unroll
                for (int j = 0; j < 4; ++j) {
                    a[j]     = (short)f2b(lo[j]);
                    a[j + 4] = (short)f2b(hi[j]);
                }
                af[r] = a;
            }
#pragma unroll
            for (int c = 0; c < 3; ++c) {
                short8 bf = *(const short8*)(Bb + (((w * 3 + c) * 2 + kk) * 64 + lane) * 16);
                acc[0][c] = MFMA16(af[0], bf, acc[0][c]);
                acc[1][c] = MFMA16(af[1], bf, acc[1][c]);
            }
        }
        __syncthreads();                             // drains vmcnt (stage) + lgkm, swap
    }
#undef STAGE

    // epilogue: bounce through LDS tile[32][200], then Kb, 4x Qb, 4x Vt (transposed)
    u16 (*tile)[200] = (u16(*)[200])smem;
#pragma unroll
    for (int r = 0; r < 2; ++r)
#pragma unroll
        for (int c = 0; c < 3; ++c)
#pragma unroll
            for (int reg = 0; reg < 4; ++reg)
                tile[r * 16 + quad * 4 + reg][(w * 3 + c) * 16 + l16] = f2b(acc[r][c][reg]);
    __syncthreads();

    const int b = mbase >> 12, t0b = mbase & 4095;
    {
        const int row = tid >> 3, cu8 = (tid & 7) * 8;
        short8 vk = *(const short8*)&tile[row][cu8];
        *(short8*)(Kb + (size_t)(mbase + row) * 64 + cu8) = vk;
        short8 vq = *(const short8*)&tile[row][64 + cu8];
#pragma unroll
        for (int r = 0; r < 4; ++r)
            *(short8*)(Qb + (size_t)r * 1048576 + (size_t)(mbase + row) * 64 + cu8) = vq;
    }
    {
        const int h = tid >> 2, toff = (tid & 3) * 8;
        short8 vv;
#pragma unroll
        for (int j = 0; j < 8; ++j) vv[j] = tile[toff + j][128 + h];
#pragma unroll
        for (int r = 0; r < 4; ++r)
            *(short8*)(Vt + (size_t)r * 1048576 + ((size_t)(b * 64 + h) << 12) + t0b + toff) = vv;
    }
}

// ---------- kernel 3: split-S flash attention, KVBLK=128, swapped QK, packed Ps.
// Chunk width 1024 (8 big-steps); pair(t,63-t) = 5 blocks -> 640-block single round.
// r20: block-uniform diag branch; l-sum via ones-MFMA (no per-step VALU adds).
#define QSWZ(row, cb) ((row) * 128 + ((cb) ^ (((row) & 7) << 4)))
#define VSWZ(row, cb) ((row) * 256 + ((cb) ^ (((row) & 15) << 4)))
__global__ __launch_bounds__(256) void attn_kernel(const u16* __restrict__ Kb,
                                                   const u16* __restrict__ Qb,
                                                   const u16* __restrict__ Vt,
                                                   u16* __restrict__ Op,
                                                   float* __restrict__ Ml) {
    const int pc = blockIdx.x;                       // 0..159 = pair*5 + c
    const int b = blockIdx.y;
    const int pair = pc / 5, c5 = pc - pair * 5;
    const int nLow = (pair >> 4) + 1;                // chunks(tLow), tLow = pair (0..31)
    const int tile  = (c5 < nLow) ? pair : (63 - pair);
    const int chunk = (c5 < nLow) ? c5 : (c5 - nLow);
    __shared__ char smem[50176];                     // Qs 16K | Vs 16K | Ps 4x4352
    const int tid = threadIdx.x;
    const int w = tid >> 6, lane = tid & 63, quad = lane >> 4, l16 = lane & 15;
    char* psB = smem + 32768 + w * 4352;             // wave-private P
    const int t0 = tile * 64;
    const int bsBeg = chunk * 8;                     // 128-wide s blocks
    const int bsEnd = min(chunk * 8 + 7, tile >> 1);
    const int bsDiag = tile >> 1;

    // replica index: simultaneous readers of an s-tile differ in `tile` -> spread x4
    const u16* Qp = Qb + (size_t)(tile & 3) * 1048576;
    const u16* Vp = Vt + (size_t)(tile & 3) * 1048576;

    // staging addresses: 1024 16B-units; Q: row=lin>>3 (128), V: row h=lin>>4 (64)
    int qd[4], vd[4];
    size_t qg[4], vg[4];
#pragma unroll
    for (int i = 0; i < 4; ++i) {
        const int lin = tid + i * 256;
        qd[i] = QSWZ(lin >> 3, (lin & 7) * 16);
        vd[i] = VSWZ(lin >> 4, (lin & 15) * 16);
        qg[i] = ((size_t)(b << 12) + (lin >> 3)) * 64 + (lin & 7) * 8;
        vg[i] = ((size_t)(b * 64 + (lin >> 4)) << 12) + (lin & 15) * 8;
    }

    short8 aK[2];
#pragma unroll
    for (int kk = 0; kk < 2; ++kk)
        aK[kk] = *(const short8*)(Kb + (size_t)((b << 12) + t0 + w * 16 + l16) * 64 + kk * 32 + quad * 8);

    short8 qr[4], vr[4];
#pragma unroll
    for (int i = 0; i < 4; ++i) {
        qr[i] = *(const short8*)(Qp + qg[i] + (size_t)bsBeg * 8192);
        vr[i] = *(const short8*)(Vp + vg[i] + bsBeg * 128);
    }

    short8 onesB;                                    // B-fragment of bf16 1.0
#pragma unroll
    for (int j = 0; j < 8; ++j) onesB[j] = (short)0x3F80;

    f32x4 lML = (f32x4)(0.0f);                       // row-sums via P @ 1
    f32x4 O[4];
#pragma unroll
    for (int ht = 0; ht < 4; ++ht) O[ht] = (f32x4)(0.0f);

    const int tg = t0 + w * 16 + l16;

    for (int bs = bsBeg; bs <= bsEnd; ++bs) {
        __syncthreads();                              // prev tile's LDS reads done
#pragma unroll
        for (int i = 0; i < 4; ++i) {
            *(short8*)(smem + qd[i]) = qr[i];
            *(short8*)(smem + 16384 + vd[i]) = vr[i];
        }
        __syncthreads();
        if (bs < bsEnd) {                             // next-tile loads fly during compute
#pragma unroll
            for (int i = 0; i < 4; ++i) {
                qr[i] = *(const short8*)(Qp + qg[i] + (size_t)(bs + 1) * 8192);
                vr[i] = *(const short8*)(Vp + vg[i] + (bs + 1) * 128);
            }
        }

        // S^T tile via swapped operands: C[m=s=nt*16+quad*4+reg][n=t=l16]
        f32x4 sc[8];
#pragma unroll
        for (int nt = 0; nt < 8; ++nt) sc[nt] = (f32x4)(0.0f);
#pragma unroll
        for (int kk = 0; kk < 2; ++kk)
#pragma unroll
            for (int nt = 0; nt < 8; ++nt) {
                short8 aq = *(const short8*)(smem + QSWZ(nt * 16 + l16, kk * 64 + quad * 16));
                sc[nt] = MFMA16(aq, aK[kk], sc[nt]);
            }

        // max-free softmax; block-uniform diag branch (mask VALU only on 1 of 8 steps)
        if (bs != bsDiag) {
#pragma unroll
            for (int nt = 0; nt < 8; ++nt) {
                s16x4 v4;
#pragma unroll
                for (int reg = 0; reg < 4; ++reg)
                    v4[reg] = (short)f2b(exp2f(sc[nt][reg] * 0.18033688011112042f));
                *(s16x4*)(psB + l16 * 272 + nt * 32 + quad * 8) = v4;
            }
        } else {
#pragma unroll
            for (int nt = 0; nt < 8; ++nt) {
                const int sgBase = bs * 128 + nt * 16 + quad * 4;
                s16x4 v4;
#pragma unroll
                for (int reg = 0; reg < 4; ++reg) {
                    float v = sc[nt][reg];
                    if (sgBase + reg > tg) v = -1e30f;
                    v4[reg] = (short)f2b(exp2f(v * 0.18033688011112042f));
                }
                *(s16x4*)(psB + l16 * 272 + nt * 32 + quad * 8) = v4;
            }
        }

        // PV: A = P (m=t=l16, k=s), B = V (n=h); +ones-MFMA row-sum. Ps wave-private.
#pragma unroll
        for (int kk = 0; kk < 4; ++kk) {
            short8 ap = *(const short8*)(psB + l16 * 272 + kk * 64 + quad * 16);
            lML = MFMA16(ap, onesB, lML);
#pragma unroll
            for (int ht = 0; ht < 4; ++ht) {
                short8 bv = *(const short8*)(smem + 16384 + VSWZ(ht * 16 + l16, kk * 64 + quad * 16));
                O[ht] = MFMA16(ap, bv, O[ht]);
            }
        }
    }

    const int slot = ((b * 64 + tile) * 4 + chunk);
    const int trow = w * 16 + quad * 4;
    if (l16 == 0) {                                  // lML[reg] = full row-sum for trow+reg
#pragma unroll
        for (int reg = 0; reg < 4; ++reg)
            Ml[(size_t)slot * 64 + trow + reg] = lML[reg];
    }
#pragma unroll
    for (int ht = 0; ht < 4; ++ht)
#pragma unroll
        for (int reg = 0; reg < 4; ++reg)
            Op[(size_t)slot * 4096 + (size_t)(trow + reg) * 64 + ht * 16 + l16] = f2b(O[ht][reg]);
}

// ---------- kernel 4: combine — plain sums over 4 chunk slots, divide
__global__ __launch_bounds__(256) void combine_kernel(const u16* __restrict__ Op,
                                                      const float* __restrict__ Ml,
                                                      float* __restrict__ out) {
    const int tid = threadIdx.x, cu = tid & 7, r0 = tid >> 3;
    const int tile = blockIdx.x, b = blockIdx.y;
    const int nch = tile / 16 + 1;
    const int slotBase = (b * 64 + tile) * 4;
#pragma unroll
    for (int i = 0; i < 2; ++i) {
        const int row = r0 + 32 * i;
        float L = 0.0f, acc[8];
#pragma unroll
        for (int j = 0; j < 8; ++j) acc[j] = 0.0f;
#pragma unroll
        for (int c = 0; c < 4; ++c) {
            const bool act = c < nch;
            float lraw = Ml[(size_t)(slotBase + c) * 64 + row];
            short8 ov = *(const short8*)(Op + (size_t)(slotBase + c) * 4096 + (size_t)row * 64 + cu * 8);
            L += act ? lraw : 0.0f;
#pragma unroll
            for (int j = 0; j < 8; ++j)
                acc[j] += act ? b2f((u16)ov[j]) : 0.0f;
        }
        float inv = 1.0f / L;
        float* dst = out + ((size_t)(b << 12) + tile * 64 + row) * 64 + cu * 8;
        *(float4*)(dst)     = make_float4(acc[0] * inv, acc[1] * inv, acc[2] * inv, acc[3] * inv);
        *(float4*)(dst + 4) = make_float4(acc[4] * inv, acc[5] * inv, acc[6] * inv, acc[7] * inv);
    }
}

extern "C" void kernel_launch(void* const* d_in, const int* in_sizes, int n_in,
                              void* d_out, int out_size, void* d_ws, size_t ws_size,
                              hipStream_t stream) {
    const float* x  = (const float*)d_in[0];
    const float* Wk = (const float*)d_in[1];
    const float* Wq = (const float*)d_in[2];
    const float* Wv = (const float*)d_in[3];

    u16* ws16 = (u16*)d_ws;
    u16* Wt = ws16;                          // 8 * 196608  = 1,572,864 u16 (3.1 MB)
    u16* Kb = Wt + 1572864;                  // 1,048,576          (2 MB)
    u16* Qb = Kb + 1048576;                  // 4 * 1,048,576      (8 MB, replicas)
    u16* Vt = Qb + 4194304;                  // 4 * 1,048,576      (8 MB, replicas)
    u16* Op = Vt + 4194304;                  // 4,194,304          (8.4 MB, 1024 slots)
    float* Ml = (float*)(Op + 8388608);      // 65,536 f32         (0.25 MB)
    // total ws ~38.6 MB (Op region oversized, harmless)

    wt_kernel<<<dim3(32, 3), 256, 0, stream>>>(Wk, Wq, Wv, Wt);
    proj_kernel<<<512, 256, 0, stream>>>(x, Wt, Kb, Qb, Vt);
    attn_kernel<<<dim3(160, 4), 256, 0, stream>>>(Kb, Qb, Vt, Op, Ml);
    combine_kernel<<<dim3(64, 4), 256, 0, stream>>>(Op, Ml, (float*)d_out);
}

// Round 11
// 149.247 us; speedup vs baseline: 1.0592x; 1.0136x over previous
//
#include <hip/hip_runtime.h>

// Head attention, B=4 T=4096 C=1024 H=64. f32 in/out, bf16 MFMA compute.
// scores = k @ q^T (reference quirk).
// Counter-backed design rules:
//  - r4..r18: see journal. r18: single dispatch round, chunk 1024 (149->147) = BEST.
//  - r19: pair-fusion REGRESSED (158, occupancy 9.3%). r20: mask-hoist + ones-MFMA
//    REGRESSED (151.3) -> ones-MFMA's serial lML chain added to the MFMA critical
//    path; removed VALU was already hidden (m114 co-scheduling).
//  - r21 (this round): r18 + mask-hoist ONLY (pure VALU deletion, no added deps).
//    Clean single-variable test of the un-confounded half of r20.

typedef __attribute__((ext_vector_type(8))) short short8;
typedef __attribute__((ext_vector_type(4))) short s16x4;
typedef __attribute__((ext_vector_type(4))) float f32x4;
typedef unsigned short u16;

#define MFMA16(A, B, C) __builtin_amdgcn_mfma_f32_16x16x32_bf16((A), (B), (C), 0, 0, 0)

__device__ __forceinline__ u16 f2b(float f) {
    __bf16 h = (__bf16)f;                     // RNE hw convert; backend pk-fuses pairs
    return __builtin_bit_cast(u16, h);
}
__device__ __forceinline__ float b2f(u16 v) {
    return __builtin_bit_cast(float, (unsigned int)v << 16);
}

__device__ __forceinline__ void gload16(const void* g, void* l) {
    __builtin_amdgcn_global_load_lds(
        (const __attribute__((address_space(1))) unsigned int*)g,
        (__attribute__((address_space(3))) unsigned int*)l, 16, 0, 0);
}

// ---------- kernel 1: W -> fragment-ordered WtF, 8 replicas.
// WtF[rep][t][kc][lane][j], t = mat*4 + tl in 0..11, kc in 0..31, lane = quad*16+l16.
// element = bf16( W_mat[ k = kc*32 + quad*8 + j ][ h = tl*16 + l16 ] )
__global__ __launch_bounds__(256) void wt_kernel(const float* __restrict__ Wk,
                                                 const float* __restrict__ Wq,
                                                 const float* __restrict__ Wv,
                                                 u16* __restrict__ WtF) {
    const int kc = blockIdx.x;       // 0..31
    const int mat = blockIdx.y;      // 0..2
    const float* W = (mat == 0) ? Wk : (mat == 1 ? Wq : Wv);
    const int tid = threadIdx.x;
    const int tl = tid >> 6, lane = tid & 63, quad = lane >> 4, l16 = lane & 15;
    short8 v;
#pragma unroll
    for (int j = 0; j < 8; ++j)
        v[j] = f2b(W[(size_t)(kc * 32 + quad * 8 + j) * 64 + tl * 16 + l16]);
    const size_t dst = ((size_t)((mat * 4 + tl) * 32 + kc) * 64 + lane) * 8;
#pragma unroll
    for (int rep = 0; rep < 8; ++rep)
        *(short8*)(WtF + (size_t)rep * 196608 + dst) = v;
}

// ---------- kernel 2: fused projection. 512 blocks x 32 rows, N=192 whole.
// LDS: As[2][32][256B] f32 (col-swizzled via source addr), Bs[2][12][2][64][16B] bf16.
// Per wave: 2 row-tiles x 3 col-tiles; BK=64 (2 MFMA k-subchunks). 2-phase pipeline.
__global__ __launch_bounds__(256) void proj_kernel(const float* __restrict__ x,
                                                   const u16* __restrict__ WtF,
                                                   u16* __restrict__ Kb,
                                                   u16* __restrict__ Qb,
                                                   u16* __restrict__ Vt) {
    __shared__ char smem[65536];                     // As: 0..16K (2x8K), Bs: 16K..64K (2x24K)
    const int tid = threadIdx.x;
    const int w = tid >> 6, lane = tid & 63, quad = lane >> 4, l16 = lane & 15;
    const int mbase = blockIdx.x * 32;
    const u16* Wrep = WtF + (size_t)(blockIdx.x & 7) * 196608;  // XCD-local replica
    const char* xblk = (const char*)x + (size_t)mbase * 4096;
    const int wbase16 = (w << 6) * 16;               // wave-uniform LDS unit base (bytes)

    f32x4 acc[2][3];
#pragma unroll
    for (int r = 0; r < 2; ++r)
#pragma unroll
        for (int c = 0; c < 3; ++c) acc[r][c] = (f32x4)(0.0f);

    // stage chunk p into buffer buf: A = 512 units (16B), B = 1536 units (16B)
#define STAGE(buf, p) do {                                                          \
        char* la = smem + (buf) * 8192;                                             \
        char* lb = smem + 16384 + (buf) * 24576;                                    \
        _Pragma("unroll")                                                           \
        for (int i = 0; i < 2; ++i) {                                               \
            int u = i * 256 + tid;                                                  \
            int row = u >> 4;                                                       \
            int cb = ((u & 15) * 16) ^ ((row & 7) << 5);                            \
            gload16(xblk + (size_t)row * 4096 + (size_t)(p) * 256 + cb,             \
                    la + i * 4096 + wbase16);                                       \
        }                                                                           \
        _Pragma("unroll")                                                           \
        for (int i = 0; i < 6; ++i) {                                               \
            int u = i * 256 + tid;                                                  \
            gload16(Wrep + (size_t)(u >> 7) * 16384 + (size_t)(p) * 1024 + (u & 127) * 8, \
                    lb + i * 4096 + wbase16);                                       \
        }                                                                           \
    } while (0)

    STAGE(0, 0);
    __syncthreads();

    for (int t = 0; t < 16; ++t) {
        const int cur = t & 1;
        if (t < 15) STAGE(cur ^ 1, t + 1);           // async prefetch next chunk
        const char* Ab = smem + cur * 8192;
        const char* Bb = smem + 16384 + cur * 24576;
#pragma unroll
        for (int kk = 0; kk < 2; ++kk) {
            short8 af[2];
#pragma unroll
            for (int r = 0; r < 2; ++r) {
                const int row = r * 16 + l16;
                const int c0 = (kk * 128 + quad * 32) ^ ((l16 & 7) << 5);
                f32x4 lo = *(const f32x4*)(Ab + row * 256 + c0);
                f32x4 hi = *(const f32x4*)(Ab + row * 256 + (c0 ^ 16));
                short8 a;
#pragma unroll
                for (int j = 0; j < 4; ++j) {
                    a[j]     = (short)f2b(lo[j]);
                    a[j + 4] = (short)f2b(hi[j]);
                }
                af[r] = a;
            }
#pragma unroll
            for (int c = 0; c < 3; ++c) {
                short8 bf = *(const short8*)(Bb + (((w * 3 + c) * 2 + kk) * 64 + lane) * 16);
                acc[0][c] = MFMA16(af[0], bf, acc[0][c]);
                acc[1][c] = MFMA16(af[1], bf, acc[1][c]);
            }
        }
        __syncthreads();                             // drains vmcnt (stage) + lgkm, swap
    }
#undef STAGE

    // epilogue: bounce through LDS tile[32][200], then Kb, 4x Qb, 4x Vt (transposed)
    u16 (*tile)[200] = (u16(*)[200])smem;
#pragma unroll
    for (int r = 0; r < 2; ++r)
#pragma unroll
        for (int c = 0; c < 3; ++c)
#pragma unroll
            for (int reg = 0; reg < 4; ++reg)
                tile[r * 16 + quad * 4 + reg][(w * 3 + c) * 16 + l16] = f2b(acc[r][c][reg]);
    __syncthreads();

    const int b = mbase >> 12, t0b = mbase & 4095;
    {
        const int row = tid >> 3, cu8 = (tid & 7) * 8;
        short8 vk = *(const short8*)&tile[row][cu8];
        *(short8*)(Kb + (size_t)(mbase + row) * 64 + cu8) = vk;
        short8 vq = *(const short8*)&tile[row][64 + cu8];
#pragma unroll
        for (int r = 0; r < 4; ++r)
            *(short8*)(Qb + (size_t)r * 1048576 + (size_t)(mbase + row) * 64 + cu8) = vq;
    }
    {
        const int h = tid >> 2, toff = (tid & 3) * 8;
        short8 vv;
#pragma unroll
        for (int j = 0; j < 8; ++j) vv[j] = tile[toff + j][128 + h];
#pragma unroll
        for (int r = 0; r < 4; ++r)
            *(short8*)(Vt + (size_t)r * 1048576 + ((size_t)(b * 64 + h) << 12) + t0b + toff) = vv;
    }
}

// ---------- kernel 3: split-S flash attention, KVBLK=128, swapped QK, packed Ps.
// Chunk width 1024 (8 big-steps); pair(t,63-t) = 5 blocks -> 640-block single round.
// r21: block-uniform diag branch only (mask VALU on 1 of 8 steps); r18 l_acc kept.
#define QSWZ(row, cb) ((row) * 128 + ((cb) ^ (((row) & 7) << 4)))
#define VSWZ(row, cb) ((row) * 256 + ((cb) ^ (((row) & 15) << 4)))
__global__ __launch_bounds__(256) void attn_kernel(const u16* __restrict__ Kb,
                                                   const u16* __restrict__ Qb,
                                                   const u16* __restrict__ Vt,
                                                   u16* __restrict__ Op,
                                                   float* __restrict__ Ml) {
    const int pc = blockIdx.x;                       // 0..159 = pair*5 + c
    const int b = blockIdx.y;
    const int pair = pc / 5, c5 = pc - pair * 5;
    const int nLow = (pair >> 4) + 1;                // chunks(tLow), tLow = pair (0..31)
    const int tile  = (c5 < nLow) ? pair : (63 - pair);
    const int chunk = (c5 < nLow) ? c5 : (c5 - nLow);
    __shared__ char smem[50176];                     // Qs 16K | Vs 16K | Ps 4x4352
    const int tid = threadIdx.x;
    const int w = tid >> 6, lane = tid & 63, quad = lane >> 4, l16 = lane & 15;
    char* psB = smem + 32768 + w * 4352;             // wave-private P
    const int t0 = tile * 64;
    const int bsBeg = chunk * 8;                     // 128-wide s blocks
    const int bsEnd = min(chunk * 8 + 7, tile >> 1);
    const int bsDiag = tile >> 1;

    // replica index: simultaneous readers of an s-tile differ in `tile` -> spread x4
    const u16* Qp = Qb + (size_t)(tile & 3) * 1048576;
    const u16* Vp = Vt + (size_t)(tile & 3) * 1048576;

    // staging addresses: 1024 16B-units; Q: row=lin>>3 (128), V: row h=lin>>4 (64)
    int qd[4], vd[4];
    size_t qg[4], vg[4];
#pragma unroll
    for (int i = 0; i < 4; ++i) {
        const int lin = tid + i * 256;
        qd[i] = QSWZ(lin >> 3, (lin & 7) * 16);
        vd[i] = VSWZ(lin >> 4, (lin & 15) * 16);
        qg[i] = ((size_t)(b << 12) + (lin >> 3)) * 64 + (lin & 7) * 8;
        vg[i] = ((size_t)(b * 64 + (lin >> 4)) << 12) + (lin & 15) * 8;
    }

    short8 aK[2];
#pragma unroll
    for (int kk = 0; kk < 2; ++kk)
        aK[kk] = *(const short8*)(Kb + (size_t)((b << 12) + t0 + w * 16 + l16) * 64 + kk * 32 + quad * 8);

    short8 qr[4], vr[4];
#pragma unroll
    for (int i = 0; i < 4; ++i) {
        qr[i] = *(const short8*)(Qp + qg[i] + (size_t)bsBeg * 8192);
        vr[i] = *(const short8*)(Vp + vg[i] + bsBeg * 128);
    }

    float l_acc = 0.0f;                              // lane's t-row = w*16+l16
    f32x4 O[4];
#pragma unroll
    for (int ht = 0; ht < 4; ++ht) O[ht] = (f32x4)(0.0f);

    const int tg = t0 + w * 16 + l16;

    for (int bs = bsBeg; bs <= bsEnd; ++bs) {
        __syncthreads();                              // prev tile's LDS reads done
#pragma unroll
        for (int i = 0; i < 4; ++i) {
            *(short8*)(smem + qd[i]) = qr[i];
            *(short8*)(smem + 16384 + vd[i]) = vr[i];
        }
        __syncthreads();
        if (bs < bsEnd) {                             // next-tile loads fly during compute
#pragma unroll
            for (int i = 0; i < 4; ++i) {
                qr[i] = *(const short8*)(Qp + qg[i] + (size_t)(bs + 1) * 8192);
                vr[i] = *(const short8*)(Vp + vg[i] + (bs + 1) * 128);
            }
        }

        // S^T tile via swapped operands: C[m=s=nt*16+quad*4+reg][n=t=l16]
        f32x4 sc[8];
#pragma unroll
        for (int nt = 0; nt < 8; ++nt) sc[nt] = (f32x4)(0.0f);
#pragma unroll
        for (int kk = 0; kk < 2; ++kk)
#pragma unroll
            for (int nt = 0; nt < 8; ++nt) {
                short8 aq = *(const short8*)(smem + QSWZ(nt * 16 + l16, kk * 64 + quad * 16));
                sc[nt] = MFMA16(aq, aK[kk], sc[nt]);
            }

        // max-free softmax; block-uniform diag branch (mask VALU only on 1 of 8 steps)
        if (bs != bsDiag) {
#pragma unroll
            for (int nt = 0; nt < 8; ++nt) {
                s16x4 v4;
#pragma unroll
                for (int reg = 0; reg < 4; ++reg) {
                    float p = exp2f(sc[nt][reg] * 0.18033688011112042f);   // exp(v/8)
                    l_acc += p;
                    v4[reg] = (short)f2b(p);
                }
                *(s16x4*)(psB + l16 * 272 + nt * 32 + quad * 8) = v4;
            }
        } else {
#pragma unroll
            for (int nt = 0; nt < 8; ++nt) {
                const int sgBase = bs * 128 + nt * 16 + quad * 4;
                s16x4 v4;
#pragma unroll
                for (int reg = 0; reg < 4; ++reg) {
                    float v = sc[nt][reg];
                    if (sgBase + reg > tg) v = -1e30f;
                    float p = exp2f(v * 0.18033688011112042f);
                    l_acc += p;
                    v4[reg] = (short)f2b(p);
                }
                *(s16x4*)(psB + l16 * 272 + nt * 32 + quad * 8) = v4;
            }
        }

        // PV: A = P (m=t=l16, k=s), B = V (n=h). Ps is wave-private.
#pragma unroll
        for (int kk = 0; kk < 4; ++kk) {
            short8 ap = *(const short8*)(psB + l16 * 272 + kk * 64 + quad * 16);
#pragma unroll
            for (int ht = 0; ht < 4; ++ht) {
                short8 bv = *(const short8*)(smem + 16384 + VSWZ(ht * 16 + l16, kk * 64 + quad * 16));
                O[ht] = MFMA16(ap, bv, O[ht]);
            }
        }
    }

    const int slot = ((b * 64 + tile) * 4 + chunk);
    {   // deferred row-sum: reduce over the 4 quads (lanes differing in bits 4-5)
        float v = l_acc;
        v += __shfl_xor(v, 16);
        v += __shfl_xor(v, 32);
        if (quad == 0) Ml[(size_t)slot * 64 + w * 16 + l16] = v;
    }
    const int trow = w * 16 + quad * 4;
#pragma unroll
    for (int ht = 0; ht < 4; ++ht)
#pragma unroll
        for (int reg = 0; reg < 4; ++reg)
            Op[(size_t)slot * 4096 + (size_t)(trow + reg) * 64 + ht * 16 + l16] = f2b(O[ht][reg]);
}

// ---------- kernel 4: combine — plain sums over 4 chunk slots, divide
__global__ __launch_bounds__(256) void combine_kernel(const u16* __restrict__ Op,
                                                      const float* __restrict__ Ml,
                                                      float* __restrict__ out) {
    const int tid = threadIdx.x, cu = tid & 7, r0 = tid >> 3;
    const int tile = blockIdx.x, b = blockIdx.y;
    const int nch = tile / 16 + 1;
    const int slotBase = (b * 64 + tile) * 4;
#pragma unroll
    for (int i = 0; i < 2; ++i) {
        const int row = r0 + 32 * i;
        float L = 0.0f, acc[8];
#pragma unroll
        for (int j = 0; j < 8; ++j) acc[j] = 0.0f;
#pragma unroll
        for (int c = 0; c < 4; ++c) {
            const bool act = c < nch;
            float lraw = Ml[(size_t)(slotBase + c) * 64 + row];
            short8 ov = *(const short8*)(Op + (size_t)(slotBase + c) * 4096 + (size_t)row * 64 + cu * 8);
            L += act ? lraw : 0.0f;
#pragma unroll
            for (int j = 0; j < 8; ++j)
                acc[j] += act ? b2f((u16)ov[j]) : 0.0f;
        }
        float inv = 1.0f / L;
        float* dst = out + ((size_t)(b << 12) + tile * 64 + row) * 64 + cu * 8;
        *(float4*)(dst)     = make_float4(acc[0] * inv, acc[1] * inv, acc[2] * inv, acc[3] * inv);
        *(float4*)(dst + 4) = make_float4(acc[4] * inv, acc[5] * inv, acc[6] * inv, acc[7] * inv);
    }
}

extern "C" void kernel_launch(void* const* d_in, const int* in_sizes, int n_in,
                              void* d_out, int out_size, void* d_ws, size_t ws_size,
                              hipStream_t stream) {
    const float* x  = (const float*)d_in[0];
    const float* Wk = (const float*)d_in[1];
    const float* Wq = (const float*)d_in[2];
    const float* Wv = (const float*)d_in[3];

    u16* ws16 = (u16*)d_ws;
    u16* Wt = ws16;                          // 8 * 196608  = 1,572,864 u16 (3.1 MB)
    u16* Kb = Wt + 1572864;                  // 1,048,576          (2 MB)
    u16* Qb = Kb + 1048576;                  // 4 * 1,048,576      (8 MB, replicas)
    u16* Vt = Qb + 4194304;                  // 4 * 1,048,576      (8 MB, replicas)
    u16* Op = Vt + 4194304;                  // 4,194,304          (8.4 MB, 1024 slots)
    float* Ml = (float*)(Op + 8388608);      // 65,536 f32         (0.25 MB)
    // total ws ~38.6 MB (Op region oversized, harmless)

    wt_kernel<<<dim3(32, 3), 256, 0, stream>>>(Wk, Wq, Wv, Wt);
    proj_kernel<<<512, 256, 0, stream>>>(x, Wt, Kb, Qb, Vt);
    attn_kernel<<<dim3(160, 4), 256, 0, stream>>>(Kb, Qb, Vt, Op, Ml);
    combine_kernel<<<dim3(64, 4), 256, 0, stream>>>(Op, Ml, (float*)d_out);
}